// Round 1
// baseline (771.539 us; speedup 1.0000x reference)
//
#include <hip/hip_runtime.h>
#include <cstdint>
#include <cstddef>

#define IN_CH 256

constexpr float BN_EPS = 1e-5f;

// ---------------- CSR build ----------------

__global__ void hist_kernel(const int* __restrict__ dst, int* __restrict__ cnt, int E) {
  int i = blockIdx.x * blockDim.x + threadIdx.x;
  if (i < E) atomicAdd(&cnt[dst[i]], 1);
}

__global__ void scan_partial(const int* __restrict__ cnt, int* __restrict__ bsum, int N) {
  __shared__ int lds[256];
  int i = blockIdx.x * 256 + threadIdx.x;
  int v = (i < N) ? cnt[i] : 0;
  lds[threadIdx.x] = v;
  __syncthreads();
  for (int s = 128; s > 0; s >>= 1) {
    if (threadIdx.x < s) lds[threadIdx.x] += lds[threadIdx.x + s];
    __syncthreads();
  }
  if (threadIdx.x == 0) bsum[blockIdx.x] = lds[0];
}

__global__ void scan_blocksums(int* bsum, int NB) {
  __shared__ int lds[512];
  int t = threadIdx.x;
  int v = (t < NB) ? bsum[t] : 0;
  lds[t] = v;
  __syncthreads();
  for (int off = 1; off < 512; off <<= 1) {
    int x = (t >= off) ? lds[t - off] : 0;
    __syncthreads();
    lds[t] += x;
    __syncthreads();
  }
  if (t < NB) bsum[t] = lds[t] - v;  // exclusive
}

__global__ void scan_final(const int* __restrict__ cnt, const int* __restrict__ bsum,
                           int* __restrict__ offs, int* __restrict__ cursor,
                           float* __restrict__ dinv, int N, int E) {
  __shared__ int lds[256];
  int t = threadIdx.x;
  int i = blockIdx.x * 256 + t;
  int v = (i < N) ? cnt[i] : 0;
  lds[t] = v;
  __syncthreads();
  for (int off = 1; off < 256; off <<= 1) {
    int x = (t >= off) ? lds[t - off] : 0;
    __syncthreads();
    lds[t] += x;
    __syncthreads();
  }
  int excl = lds[t] - v + bsum[blockIdx.x];
  if (i < N) {
    offs[i] = excl;
    cursor[i] = excl;
    dinv[i] = rsqrtf((float)(v + 1));  // +1 self loop; always > 0
  }
  if (i == N - 1) offs[N] = excl + v;
}

__global__ void fill_kernel(const int* __restrict__ src, const int* __restrict__ dst,
                            int* __restrict__ cursor, int* __restrict__ srcs, int E) {
  int i = blockIdx.x * blockDim.x + threadIdx.x;
  if (i < E) {
    int d = dst[i];
    int p = atomicAdd(&cursor[d], 1);
    srcs[p] = src[i];
  }
}

// ---------------- fp32 tiled GEMM, epilogue scales row by dinv ----------------
// Out[r, c] = dinv[r] * sum_k A[r,k] * W[k,c]

template <int BM, int BN, int BK, int TM, int TN>
__global__ __launch_bounds__(256) void sgemm_dinv(const float* __restrict__ A,
                                                  const float* __restrict__ W,
                                                  const float* __restrict__ dinv,
                                                  float* __restrict__ Out, int M, int K, int N) {
  __shared__ float As[BK][BM];
  __shared__ float Bs[BK][BN];
  constexpr int NT = (BM / TM) * (BN / TN);  // 256
  const int tid = threadIdx.x;
  const int tx = tid % (BN / TN);
  const int ty = tid / (BN / TN);
  const int row0 = blockIdx.x * BM;
  const int col0 = blockIdx.y * BN;

  float acc[TM][TN] = {};

  for (int k0 = 0; k0 < K; k0 += BK) {
    // A tile: BM x BK, store transposed As[k][m]
#pragma unroll
    for (int g = tid; g < BM * BK / 4; g += NT) {
      int r = g / (BK / 4), kq = g % (BK / 4);
      float4 v = {0.f, 0.f, 0.f, 0.f};
      if (row0 + r < M) v = *(const float4*)&A[(size_t)(row0 + r) * K + k0 + 4 * kq];
      As[4 * kq + 0][r] = v.x;
      As[4 * kq + 1][r] = v.y;
      As[4 * kq + 2][r] = v.z;
      As[4 * kq + 3][r] = v.w;
    }
    // B tile: BK x BN (K, N multiples of BK/BN for our shapes)
#pragma unroll
    for (int g = tid; g < BK * BN / 4; g += NT) {
      int r = g / (BN / 4), cq = g % (BN / 4);
      *(float4*)&Bs[r][4 * cq] = *(const float4*)&W[(size_t)(k0 + r) * N + col0 + 4 * cq];
    }
    __syncthreads();

#pragma unroll
    for (int k = 0; k < BK; k++) {
      float a[TM], b[TN];
#pragma unroll
      for (int i = 0; i < TM; i += 4) *(float4*)&a[i] = *(const float4*)&As[k][ty * TM + i];
#pragma unroll
      for (int j = 0; j < TN; j += 4) *(float4*)&b[j] = *(const float4*)&Bs[k][tx * TN + j];
#pragma unroll
      for (int i = 0; i < TM; i++)
#pragma unroll
        for (int j = 0; j < TN; j++) acc[i][j] = fmaf(a[i], b[j], acc[i][j]);
    }
    __syncthreads();
  }

#pragma unroll
  for (int i = 0; i < TM; i++) {
    int r = row0 + ty * TM + i;
    if (r >= M) break;
    float dv = dinv[r];
#pragma unroll
    for (int j = 0; j < TN; j += 4) {
      float4 v;
      v.x = acc[i][j + 0] * dv;
      v.y = acc[i][j + 1] * dv;
      v.z = acc[i][j + 2] * dv;
      v.w = acc[i][j + 3] * dv;
      *(float4*)&Out[(size_t)r * N + col0 + tx * TN + j] = v;
    }
  }
}

// ---------------- aggregation: one wave per node ----------------
// out[i,:] = dinv[i] * (g[i,:] + sum_{e in CSR[i]} g[srcs[e],:]) (+ bias)

template <int C>
__global__ __launch_bounds__(256) void agg_kernel(const float* __restrict__ g,
                                                  const int* __restrict__ offs,
                                                  const int* __restrict__ srcs,
                                                  const float* __restrict__ dinv,
                                                  const float* __restrict__ bias,
                                                  float* __restrict__ out, int N) {
  int node = blockIdx.x * 4 + (threadIdx.x >> 6);
  if (node >= N) return;
  int lane = threadIdx.x & 63;

  if constexpr (C == 128) {
    float2 acc = *(const float2*)&g[(size_t)node * C + lane * 2];
    int e0 = offs[node], e1 = offs[node + 1];
    int e = e0;
    for (; e + 4 <= e1; e += 4) {
      int s0 = srcs[e], s1 = srcs[e + 1], s2 = srcs[e + 2], s3 = srcs[e + 3];
      float2 t0 = *(const float2*)&g[(size_t)s0 * C + lane * 2];
      float2 t1 = *(const float2*)&g[(size_t)s1 * C + lane * 2];
      float2 t2 = *(const float2*)&g[(size_t)s2 * C + lane * 2];
      float2 t3 = *(const float2*)&g[(size_t)s3 * C + lane * 2];
      acc.x += (t0.x + t1.x) + (t2.x + t3.x);
      acc.y += (t0.y + t1.y) + (t2.y + t3.y);
    }
    for (; e < e1; e++) {
      int s = srcs[e];
      float2 t = *(const float2*)&g[(size_t)s * C + lane * 2];
      acc.x += t.x;
      acc.y += t.y;
    }
    float dv = dinv[node];
    float2 o;
    o.x = acc.x * dv;
    o.y = acc.y * dv;
    if (bias) {
      o.x += bias[lane * 2 + 0];
      o.y += bias[lane * 2 + 1];
    }
    *(float2*)&out[(size_t)node * C + lane * 2] = o;
  } else {  // C == 64
    float acc = g[(size_t)node * C + lane];
    int e0 = offs[node], e1 = offs[node + 1];
    int e = e0;
    for (; e + 4 <= e1; e += 4) {
      int s0 = srcs[e], s1 = srcs[e + 1], s2 = srcs[e + 2], s3 = srcs[e + 3];
      float t0 = g[(size_t)s0 * C + lane];
      float t1 = g[(size_t)s1 * C + lane];
      float t2 = g[(size_t)s2 * C + lane];
      float t3 = g[(size_t)s3 * C + lane];
      acc += (t0 + t1) + (t2 + t3);
    }
    for (; e < e1; e++) acc += g[(size_t)srcs[e] * C + lane];
    float dv = dinv[node];
    float o = acc * dv + (bias ? bias[lane] : 0.f);
    out[(size_t)node * C + lane] = o;
  }
}

// ---------------- BatchNorm ----------------

template <int C>
__global__ void bn_stats(const float* __restrict__ x, float* __restrict__ stat, int N) {
  int c = threadIdx.x;  // blockDim = C
  int chunk = (N + gridDim.x - 1) / gridDim.x;
  int r0 = blockIdx.x * chunk;
  int r1 = min(N, r0 + chunk);
  float s = 0.f, q = 0.f;
  for (int r = r0; r < r1; r++) {
    float v = x[(size_t)r * C + c];
    s += v;
    q += v * v;
  }
  atomicAdd(&stat[c], s);
  atomicAdd(&stat[C + c], q);
}

template <int C>
__global__ void bn_finalize(const float* __restrict__ stat, const float* __restrict__ gamma,
                            const float* __restrict__ beta, float* __restrict__ ss, int N) {
  int c = threadIdx.x;
  if (c >= C) return;
  float mu = stat[c] / (float)N;
  float var = stat[C + c] / (float)N - mu * mu;
  float rs = rsqrtf(var + BN_EPS);
  float sc = gamma[c] * rs;
  ss[c] = sc;
  ss[C + c] = beta[c] - mu * sc;
}

template <int C>
__global__ void bn_relu(const float* __restrict__ x, const float* __restrict__ ss,
                        float* __restrict__ y, int total) {
  int i = blockIdx.x * blockDim.x + threadIdx.x;  // float4 index
  if (i * 4 >= total) return;
  float4 v = *(const float4*)&x[(size_t)i * 4];
  int c = (i * 4) % C;
  float4 r;
  r.x = fmaxf(0.f, fmaf(v.x, ss[c + 0], ss[C + c + 0]));
  r.y = fmaxf(0.f, fmaf(v.y, ss[c + 1], ss[C + c + 1]));
  r.z = fmaxf(0.f, fmaf(v.z, ss[c + 2], ss[C + c + 2]));
  r.w = fmaxf(0.f, fmaf(v.w, ss[c + 3], ss[C + c + 3]));
  *(float4*)&y[(size_t)i * 4] = r;
}

// ---------------- launch ----------------

extern "C" void kernel_launch(void* const* d_in, const int* in_sizes, int n_in, void* d_out,
                              int out_size, void* d_ws, size_t ws_size, hipStream_t stream) {
  const float* x = (const float*)d_in[0];
  const int* ei = (const int*)d_in[1];
  const float* W1 = (const float*)d_in[2];
  // b1 = d_in[3]  (cancels in BN)
  const float* gamma1 = (const float*)d_in[4];
  const float* beta1 = (const float*)d_in[5];
  const float* W2 = (const float*)d_in[6];
  // b2 = d_in[7]  (cancels in BN)
  const float* gamma2 = (const float*)d_in[8];
  const float* beta2 = (const float*)d_in[9];
  const float* W3 = (const float*)d_in[10];
  const float* b3 = (const float*)d_in[11];
  float* out = (float*)d_out;

  const int N = in_sizes[0] / IN_CH;  // 100000
  const int E = in_sizes[1] / 2;      // 1600000
  const int* e_src = ei;
  const int* e_dst = ei + E;

  // workspace layout
  char* ws = (char*)d_ws;
  size_t off = 0;
  auto alloc = [&](size_t bytes) {
    size_t r = off;
    off += (bytes + 1023) & ~(size_t)1023;
    return r;
  };
  int* cnt = (int*)(ws + alloc((size_t)N * 4));
  int* bsum = (int*)(ws + alloc(512 * 4));
  int* offs = (int*)(ws + alloc((size_t)(N + 1) * 4));
  int* cursor = (int*)(ws + alloc((size_t)N * 4));
  float* dinv = (float*)(ws + alloc((size_t)N * 4));
  int* srcs = (int*)(ws + alloc((size_t)E * 4));
  float* stat1 = (float*)(ws + alloc(256 * 4));  // sum[128], sumsq[128]
  float* stat2 = (float*)(ws + alloc(128 * 4));  // sum[64], sumsq[64]
  float* ss1 = (float*)(ws + alloc(256 * 4));
  float* ss2 = (float*)(ws + alloc(128 * 4));
  float* bufG = (float*)(ws + alloc((size_t)N * 128 * 4));
  float* bufH = (float*)(ws + alloc((size_t)N * 128 * 4));
  float* h2a = bufH;                       // layer-2 gemm out (N x 64)
  float* h2b = bufH + (size_t)N * 64;      // layer-2 agg out  (N x 64)

  hipMemsetAsync(cnt, 0, (size_t)N * 4, stream);
  hipMemsetAsync(stat1, 0, 256 * 4, stream);
  hipMemsetAsync(stat2, 0, 128 * 4, stream);

  const int NB = (N + 255) / 256;  // 391
  hist_kernel<<<(E + 255) / 256, 256, 0, stream>>>(e_dst, cnt, E);
  scan_partial<<<NB, 256, 0, stream>>>(cnt, bsum, N);
  scan_blocksums<<<1, 512, 0, stream>>>(bsum, NB);
  scan_final<<<NB, 256, 0, stream>>>(cnt, bsum, offs, cursor, dinv, N, E);
  fill_kernel<<<(E + 255) / 256, 256, 0, stream>>>(e_src, e_dst, cursor, srcs, E);

  const int gM = (N + 127) / 128;      // 782
  const int gAgg = (N + 3) / 4;        // 25000

  // ---- layer 1: 256 -> 128 ----
  sgemm_dinv<128, 128, 16, 8, 8><<<dim3(gM, 1), 256, 0, stream>>>(x, W1, dinv, bufG, N, 256, 128);
  agg_kernel<128><<<gAgg, 256, 0, stream>>>(bufG, offs, srcs, dinv, nullptr, bufH, N);
  bn_stats<128><<<512, 128, 0, stream>>>(bufH, stat1, N);
  bn_finalize<128><<<1, 128, 0, stream>>>(stat1, gamma1, beta1, ss1, N);
  bn_relu<128><<<(N * 128 / 4 + 255) / 256, 256, 0, stream>>>(bufH, ss1, bufG, N * 128);

  // ---- layer 2: 128 -> 64 ----
  sgemm_dinv<128, 64, 16, 8, 4><<<dim3(gM, 1), 256, 0, stream>>>(bufG, W2, dinv, h2a, N, 128, 64);
  agg_kernel<64><<<gAgg, 256, 0, stream>>>(h2a, offs, srcs, dinv, nullptr, h2b, N);
  bn_stats<64><<<512, 64, 0, stream>>>(h2b, stat2, N);
  bn_finalize<64><<<1, 64, 0, stream>>>(stat2, gamma2, beta2, ss2, N);
  bn_relu<64><<<(N * 64 / 4 + 255) / 256, 256, 0, stream>>>(h2b, ss2, bufG, N * 64);

  // ---- layer 3: 64 -> 64 ----
  sgemm_dinv<128, 64, 16, 8, 4><<<dim3(gM, 1), 256, 0, stream>>>(bufG, W3, dinv, h2a, N, 64, 64);
  agg_kernel<64><<<gAgg, 256, 0, stream>>>(h2a, offs, srcs, dinv, b3, out, N);
}

// Round 2
// 595.402 us; speedup vs baseline: 1.2958x; 1.2958x over previous
//
#include <hip/hip_runtime.h>
#include <cstdint>
#include <cstddef>

#define IN_CH 256

constexpr float BN_EPS = 1e-5f;

using u16x4 = __attribute__((ext_vector_type(4))) unsigned short;
using u16x8 = __attribute__((ext_vector_type(8))) unsigned short;
using bf16x8 = __attribute__((ext_vector_type(8))) short;
using f32x4 = __attribute__((ext_vector_type(4))) float;

__device__ __forceinline__ unsigned short f2bf_rne(float x) {
  unsigned u = __builtin_bit_cast(unsigned, x);
  unsigned r = u + 0x7FFFu + ((u >> 16) & 1u);
  return (unsigned short)(r >> 16);
}
__device__ __forceinline__ float bf2f(unsigned short h) {
  unsigned u = ((unsigned)h) << 16;
  return __builtin_bit_cast(float, u);
}

// ---------------- CSR build ----------------

__global__ void hist_kernel(const int* __restrict__ dst, int* __restrict__ cnt, int E) {
  int i = blockIdx.x * blockDim.x + threadIdx.x;
  if (i < E) atomicAdd(&cnt[dst[i]], 1);
}

__global__ void scan_partial(const int* __restrict__ cnt, int* __restrict__ bsum, int N) {
  __shared__ int lds[256];
  int i = blockIdx.x * 256 + threadIdx.x;
  int v = (i < N) ? cnt[i] : 0;
  lds[threadIdx.x] = v;
  __syncthreads();
  for (int s = 128; s > 0; s >>= 1) {
    if (threadIdx.x < s) lds[threadIdx.x] += lds[threadIdx.x + s];
    __syncthreads();
  }
  if (threadIdx.x == 0) bsum[blockIdx.x] = lds[0];
}

__global__ void scan_blocksums(int* bsum, int NB) {
  __shared__ int lds[512];
  int t = threadIdx.x;
  int v = (t < NB) ? bsum[t] : 0;
  lds[t] = v;
  __syncthreads();
  for (int off = 1; off < 512; off <<= 1) {
    int x = (t >= off) ? lds[t - off] : 0;
    __syncthreads();
    lds[t] += x;
    __syncthreads();
  }
  if (t < NB) bsum[t] = lds[t] - v;  // exclusive
}

__global__ void scan_final(const int* __restrict__ cnt, const int* __restrict__ bsum,
                           int* __restrict__ offs, int* __restrict__ cursor,
                           float* __restrict__ dinv, int N, int E) {
  __shared__ int lds[256];
  int t = threadIdx.x;
  int i = blockIdx.x * 256 + t;
  int v = (i < N) ? cnt[i] : 0;
  lds[t] = v;
  __syncthreads();
  for (int off = 1; off < 256; off <<= 1) {
    int x = (t >= off) ? lds[t - off] : 0;
    __syncthreads();
    lds[t] += x;
    __syncthreads();
  }
  int excl = lds[t] - v + bsum[blockIdx.x];
  if (i < N) {
    offs[i] = excl;
    cursor[i] = excl;
    dinv[i] = rsqrtf((float)(v + 1));  // +1 self loop
  }
  if (i == N - 1) offs[N] = excl + v;
}

__global__ void fill_kernel(const int* __restrict__ src, const int* __restrict__ dst,
                            int* __restrict__ cursor, int* __restrict__ srcs, int E) {
  int i = blockIdx.x * blockDim.x + threadIdx.x;
  if (i < E) {
    int d = dst[i];
    int p = atomicAdd(&cursor[d], 1);
    srcs[p] = src[i];
  }
}

// ---------------- weight prep: transpose + hi/lo bf16 split ----------------
// Wt_hi[n*K + k] = bf16(W[k*N + n]); Wt_lo = bf16(residual)

__global__ void wprep(const float* __restrict__ W, unsigned short* __restrict__ hi,
                      unsigned short* __restrict__ lo, int K, int N) {
  int i = blockIdx.x * 256 + threadIdx.x;
  if (i >= K * N) return;
  int k = i / N, n = i - k * N;
  float v = W[i];
  unsigned short h = f2bf_rne(v);
  hi[(size_t)n * K + k] = h;
  lo[(size_t)n * K + k] = f2bf_rne(v - bf2f(h));
}

// ---------------- MFMA GEMM: Out[r,c] = bf16( dinv[r] * sum_k a(r,k)*W[k,c] ) ----------------
// a(r,k) = BNRELU ? relu(A[r,k]*ss[k] + ss[K+k]) : A[r,k]
// A fp32 row-major [M,K]; weights pre-transposed bf16 split [BN,K] (k-contiguous).
// split fp32 -> hi+lo bf16, 3 MFMAs per tile (hi*hi + lo*hi + hi*lo).

template <int K, int BN, bool BNRELU>
__global__ __launch_bounds__(256) void mfma_gemm(const float* __restrict__ A,
                                                 const unsigned short* __restrict__ Bt_hi,
                                                 const unsigned short* __restrict__ Bt_lo,
                                                 const float* __restrict__ ss,
                                                 const float* __restrict__ dinv,
                                                 unsigned short* __restrict__ Out, int M) {
  constexpr int BM = 128;
  __shared__ unsigned short Ah[BM * 32];
  __shared__ unsigned short Al[BM * 32];
  __shared__ unsigned short Bh[BN * 32];
  __shared__ unsigned short Bl[BN * 32];

  const int tid = threadIdx.x;
  const int wave = tid >> 6;
  const int lane = tid & 63;
  const int lg = lane >> 4;  // k-group / row-group
  const int lr = lane & 15;  // row (A) / col (B,D)
  const int row0 = blockIdx.x * BM;

  f32x4 acc[2][BN / 16];
#pragma unroll
  for (int f = 0; f < 2; ++f)
#pragma unroll
    for (int j = 0; j < BN / 16; ++j) acc[f][j] = (f32x4){0.f, 0.f, 0.f, 0.f};

  for (int k0 = 0; k0 < K; k0 += 32) {
    __syncthreads();  // previous iteration's reads done before overwrite
    // ---- stage A: 128 rows x 32 k, fp32 -> hi/lo bf16, XOR-swizzled chunks ----
#pragma unroll
    for (int it = 0; it < 4; ++it) {
      int m = it * 32 + (tid >> 3);
      int c2 = tid & 7;  // which 4-k group
      float4 v = {0.f, 0.f, 0.f, 0.f};
      if (row0 + m < M) v = *(const float4*)&A[(size_t)(row0 + m) * K + k0 + c2 * 4];
      if constexpr (BNRELU) {
        int kk = k0 + c2 * 4;
        float4 sc = *(const float4*)&ss[kk];
        float4 sh = *(const float4*)&ss[K + kk];
        v.x = fmaxf(0.f, fmaf(v.x, sc.x, sh.x));
        v.y = fmaxf(0.f, fmaf(v.y, sc.y, sh.y));
        v.z = fmaxf(0.f, fmaf(v.z, sc.z, sh.z));
        v.w = fmaxf(0.f, fmaf(v.w, sc.w, sh.w));
      }
      float vv[4] = {v.x, v.y, v.z, v.w};
      u16x4 h4, l4;
#pragma unroll
      for (int i = 0; i < 4; ++i) {
        unsigned short h = f2bf_rne(vv[i]);
        h4[i] = h;
        l4[i] = f2bf_rne(vv[i] - bf2f(h));
      }
      int pr = (m >> 1) & 3;
      int base = m * 32 + (((c2 >> 1) ^ pr) * 8) + (c2 & 1) * 4;
      *(u16x4*)&Ah[base] = h4;
      *(u16x4*)&Al[base] = l4;
    }
    // ---- stage B: BN rows x 32 k (already bf16, k-contiguous) ----
#pragma unroll
    for (int it = 0; it < BN / 64; ++it) {
      int n = it * 64 + (tid >> 2);
      int c = tid & 3;
      int pr = (n >> 1) & 3;
      int base = n * 32 + ((c ^ pr) * 8);
      *(u16x8*)&Bh[base] = *(const u16x8*)&Bt_hi[(size_t)n * K + k0 + c * 8];
      *(u16x8*)&Bl[base] = *(const u16x8*)&Bt_lo[(size_t)n * K + k0 + c * 8];
    }
    __syncthreads();

    // ---- fragments + MFMA ----
    bf16x8 afh[2], afl[2];
#pragma unroll
    for (int f = 0; f < 2; ++f) {
      int m = wave * 32 + f * 16 + lr;
      int pr = (m >> 1) & 3;
      int base = m * 32 + ((lg ^ pr) * 8);
      afh[f] = *(const bf16x8*)&Ah[base];
      afl[f] = *(const bf16x8*)&Al[base];
    }
#pragma unroll
    for (int j = 0; j < BN / 16; ++j) {
      int n = j * 16 + lr;
      int pr = (n >> 1) & 3;
      int base = n * 32 + ((lg ^ pr) * 8);
      bf16x8 bh = *(const bf16x8*)&Bh[base];
      bf16x8 bl = *(const bf16x8*)&Bl[base];
#pragma unroll
      for (int f = 0; f < 2; ++f) {
        acc[f][j] = __builtin_amdgcn_mfma_f32_16x16x32_bf16(afh[f], bh, acc[f][j], 0, 0, 0);
        acc[f][j] = __builtin_amdgcn_mfma_f32_16x16x32_bf16(afl[f], bh, acc[f][j], 0, 0, 0);
        acc[f][j] = __builtin_amdgcn_mfma_f32_16x16x32_bf16(afh[f], bl, acc[f][j], 0, 0, 0);
      }
    }
  }

  // ---- epilogue: scale by dinv[row], store bf16 ----
#pragma unroll
  for (int f = 0; f < 2; ++f) {
#pragma unroll
    for (int r4 = 0; r4 < 4; ++r4) {
      int r = row0 + wave * 32 + f * 16 + lg * 4 + r4;
      if (r >= M) continue;
      float dv = dinv[r];
      size_t rb = (size_t)r * BN + lr;
#pragma unroll
      for (int j = 0; j < BN / 16; ++j) Out[rb + j * 16] = f2bf_rne(acc[f][j][r4] * dv);
    }
  }
}

// ---------------- aggregation (bf16 messages -> fp32) ----------------
// out[i,:] = dinv[i] * (g[i,:] + sum_{e} g[srcs[e],:]) (+ bias)

__global__ __launch_bounds__(256) void agg128(const unsigned short* __restrict__ g,
                                              const int* __restrict__ offs,
                                              const int* __restrict__ srcs,
                                              const float* __restrict__ dinv,
                                              float* __restrict__ out, int N) {
  int node = blockIdx.x * 4 + (threadIdx.x >> 6);
  if (node >= N) return;
  int lane = threadIdx.x & 63;
  const size_t co = (size_t)lane * 2;

  unsigned us = *(const unsigned*)&g[(size_t)node * 128 + co];
  float ax = __builtin_bit_cast(float, us << 16);
  float ay = __builtin_bit_cast(float, us & 0xffff0000u);

  int e0 = offs[node], e1 = offs[node + 1];
  int e = e0;
  for (; e + 4 <= e1; e += 4) {
    int s0 = srcs[e], s1 = srcs[e + 1], s2 = srcs[e + 2], s3 = srcs[e + 3];
    unsigned u0 = *(const unsigned*)&g[(size_t)s0 * 128 + co];
    unsigned u1 = *(const unsigned*)&g[(size_t)s1 * 128 + co];
    unsigned u2 = *(const unsigned*)&g[(size_t)s2 * 128 + co];
    unsigned u3 = *(const unsigned*)&g[(size_t)s3 * 128 + co];
    ax += __builtin_bit_cast(float, u0 << 16) + __builtin_bit_cast(float, u1 << 16) +
          __builtin_bit_cast(float, u2 << 16) + __builtin_bit_cast(float, u3 << 16);
    ay += __builtin_bit_cast(float, u0 & 0xffff0000u) + __builtin_bit_cast(float, u1 & 0xffff0000u) +
          __builtin_bit_cast(float, u2 & 0xffff0000u) + __builtin_bit_cast(float, u3 & 0xffff0000u);
  }
  for (; e < e1; ++e) {
    unsigned u = *(const unsigned*)&g[(size_t)srcs[e] * 128 + co];
    ax += __builtin_bit_cast(float, u << 16);
    ay += __builtin_bit_cast(float, u & 0xffff0000u);
  }
  float dv = dinv[node];
  float2 o = {ax * dv, ay * dv};
  *(float2*)&out[(size_t)node * 128 + co] = o;
}

// C=64: half-wave per edge (2 edges in flight), cross-half reduce at end.
__global__ __launch_bounds__(256) void agg64(const unsigned short* __restrict__ g,
                                             const int* __restrict__ offs,
                                             const int* __restrict__ srcs,
                                             const float* __restrict__ dinv,
                                             const float* __restrict__ bias,
                                             float* __restrict__ out, int N) {
  int node = blockIdx.x * 4 + (threadIdx.x >> 6);
  if (node >= N) return;
  int lane = threadIdx.x & 63;
  int half = lane >> 5;
  int li = lane & 31;
  const size_t co = (size_t)li * 2;

  float ax = 0.f, ay = 0.f;
  if (half == 0) {
    unsigned us = *(const unsigned*)&g[(size_t)node * 64 + co];
    ax = __builtin_bit_cast(float, us << 16);
    ay = __builtin_bit_cast(float, us & 0xffff0000u);
  }
  int e0 = offs[node], e1 = offs[node + 1];
  int e = e0 + half;
  for (; e + 6 < e1; e += 8) {
    int s0 = srcs[e], s1 = srcs[e + 2], s2 = srcs[e + 4], s3 = srcs[e + 6];
    unsigned u0 = *(const unsigned*)&g[(size_t)s0 * 64 + co];
    unsigned u1 = *(const unsigned*)&g[(size_t)s1 * 64 + co];
    unsigned u2 = *(const unsigned*)&g[(size_t)s2 * 64 + co];
    unsigned u3 = *(const unsigned*)&g[(size_t)s3 * 64 + co];
    ax += __builtin_bit_cast(float, u0 << 16) + __builtin_bit_cast(float, u1 << 16) +
          __builtin_bit_cast(float, u2 << 16) + __builtin_bit_cast(float, u3 << 16);
    ay += __builtin_bit_cast(float, u0 & 0xffff0000u) + __builtin_bit_cast(float, u1 & 0xffff0000u) +
          __builtin_bit_cast(float, u2 & 0xffff0000u) + __builtin_bit_cast(float, u3 & 0xffff0000u);
  }
  for (; e < e1; e += 2) {
    unsigned u = *(const unsigned*)&g[(size_t)srcs[e] * 64 + co];
    ax += __builtin_bit_cast(float, u << 16);
    ay += __builtin_bit_cast(float, u & 0xffff0000u);
  }
  ax += __shfl_xor(ax, 32);
  ay += __shfl_xor(ay, 32);
  if (half == 0) {
    float dv = dinv[node];
    float ox = ax * dv, oy = ay * dv;
    if (bias) {
      ox += bias[co];
      oy += bias[co + 1];
    }
    float2 o = {ox, oy};
    *(float2*)&out[(size_t)node * 64 + co] = o;
  }
}

// ---------------- BatchNorm ----------------

template <int C>
__global__ void bn_stats(const float* __restrict__ x, float* __restrict__ stat, int N) {
  int c = threadIdx.x;  // blockDim = C
  int chunk = (N + gridDim.x - 1) / gridDim.x;
  int r0 = blockIdx.x * chunk;
  int r1 = min(N, r0 + chunk);
  float s = 0.f, q = 0.f;
  for (int r = r0; r < r1; r++) {
    float v = x[(size_t)r * C + c];
    s += v;
    q += v * v;
  }
  atomicAdd(&stat[c], s);
  atomicAdd(&stat[C + c], q);
}

template <int C>
__global__ void bn_finalize(const float* __restrict__ stat, const float* __restrict__ gamma,
                            const float* __restrict__ beta, float* __restrict__ ss, int N) {
  int c = threadIdx.x;
  if (c >= C) return;
  float mu = stat[c] / (float)N;
  float var = stat[C + c] / (float)N - mu * mu;
  float rs = rsqrtf(var + BN_EPS);
  float sc = gamma[c] * rs;
  ss[c] = sc;
  ss[C + c] = beta[c] - mu * sc;
}

// ---------------- launch ----------------

extern "C" void kernel_launch(void* const* d_in, const int* in_sizes, int n_in, void* d_out,
                              int out_size, void* d_ws, size_t ws_size, hipStream_t stream) {
  const float* x = (const float*)d_in[0];
  const int* ei = (const int*)d_in[1];
  const float* W1 = (const float*)d_in[2];
  // b1, b2 cancel in BN
  const float* gamma1 = (const float*)d_in[4];
  const float* beta1 = (const float*)d_in[5];
  const float* W2 = (const float*)d_in[6];
  const float* gamma2 = (const float*)d_in[8];
  const float* beta2 = (const float*)d_in[9];
  const float* W3 = (const float*)d_in[10];
  const float* b3 = (const float*)d_in[11];
  float* out = (float*)d_out;

  const int N = in_sizes[0] / IN_CH;  // 100000
  const int E = in_sizes[1] / 2;      // 1600000
  const int* e_src = ei;
  const int* e_dst = ei + E;

  char* ws = (char*)d_ws;
  size_t off = 0;
  auto alloc = [&](size_t bytes) {
    size_t r = off;
    off += (bytes + 1023) & ~(size_t)1023;
    return r;
  };
  int* cnt = (int*)(ws + alloc((size_t)N * 4));
  int* bsum = (int*)(ws + alloc(512 * 4));
  int* offs = (int*)(ws + alloc((size_t)(N + 1) * 4));
  int* cursor = (int*)(ws + alloc((size_t)N * 4));
  float* dinv = (float*)(ws + alloc((size_t)N * 4));
  int* srcs = (int*)(ws + alloc((size_t)E * 4));
  unsigned short* Wt1h = (unsigned short*)(ws + alloc(256 * 128 * 2));
  unsigned short* Wt1l = (unsigned short*)(ws + alloc(256 * 128 * 2));
  unsigned short* Wt2h = (unsigned short*)(ws + alloc(128 * 64 * 2));
  unsigned short* Wt2l = (unsigned short*)(ws + alloc(128 * 64 * 2));
  unsigned short* Wt3h = (unsigned short*)(ws + alloc(64 * 64 * 2));
  unsigned short* Wt3l = (unsigned short*)(ws + alloc(64 * 64 * 2));
  float* stat1 = (float*)(ws + alloc(256 * 4));
  float* stat2 = (float*)(ws + alloc(128 * 4));
  float* ss1 = (float*)(ws + alloc(256 * 4));
  float* ss2 = (float*)(ws + alloc(128 * 4));
  unsigned short* g = (unsigned short*)(ws + alloc((size_t)N * 128 * 2));  // bf16 messages
  float* h = (float*)(ws + alloc((size_t)N * 128 * 4));                    // fp32 aggregated

  hipMemsetAsync(cnt, 0, (size_t)N * 4, stream);
  hipMemsetAsync(stat1, 0, 256 * 4, stream);
  hipMemsetAsync(stat2, 0, 128 * 4, stream);

  const int NB = (N + 255) / 256;
  hist_kernel<<<(E + 255) / 256, 256, 0, stream>>>(e_dst, cnt, E);
  scan_partial<<<NB, 256, 0, stream>>>(cnt, bsum, N);
  scan_blocksums<<<1, 512, 0, stream>>>(bsum, NB);
  scan_final<<<NB, 256, 0, stream>>>(cnt, bsum, offs, cursor, dinv, N, E);
  fill_kernel<<<(E + 255) / 256, 256, 0, stream>>>(e_src, e_dst, cursor, srcs, E);

  wprep<<<(256 * 128 + 255) / 256, 256, 0, stream>>>(W1, Wt1h, Wt1l, 256, 128);
  wprep<<<(128 * 64 + 255) / 256, 256, 0, stream>>>(W2, Wt2h, Wt2l, 128, 64);
  wprep<<<(64 * 64 + 255) / 256, 256, 0, stream>>>(W3, Wt3h, Wt3l, 64, 64);

  const int gM = (N + 127) / 128;  // 782
  const int gAgg = (N + 3) / 4;    // 25000

  // ---- layer 1: 256 -> 128 ----
  mfma_gemm<256, 128, false><<<gM, 256, 0, stream>>>(x, Wt1h, Wt1l, nullptr, dinv, g, N);
  agg128<<<gAgg, 256, 0, stream>>>(g, offs, srcs, dinv, h, N);
  bn_stats<128><<<512, 128, 0, stream>>>(h, stat1, N);
  bn_finalize<128><<<1, 128, 0, stream>>>(stat1, gamma1, beta1, ss1, N);

  // ---- layer 2: 128 -> 64 (BN+ReLU fused into A staging) ----
  mfma_gemm<128, 64, true><<<gM, 256, 0, stream>>>(h, Wt2h, Wt2l, ss1, dinv, g, N);
  agg64<<<gAgg, 256, 0, stream>>>(g, offs, srcs, dinv, nullptr, h, N);
  bn_stats<64><<<512, 64, 0, stream>>>(h, stat2, N);
  bn_finalize<64><<<1, 64, 0, stream>>>(stat2, gamma2, beta2, ss2, N);

  // ---- layer 3: 64 -> 64 ----
  mfma_gemm<64, 64, true><<<gM, 256, 0, stream>>>(h, Wt3h, Wt3l, ss2, dinv, g, N);
  agg64<<<gAgg, 256, 0, stream>>>(g, offs, srcs, dinv, b3, out, N);
}

// Round 3
// 514.999 us; speedup vs baseline: 1.4981x; 1.1561x over previous
//
#include <hip/hip_runtime.h>
#include <cstdint>
#include <cstddef>

#define IN_CH 256

constexpr float BN_EPS = 1e-5f;

using u16x4 = __attribute__((ext_vector_type(4))) unsigned short;
using u16x8 = __attribute__((ext_vector_type(8))) unsigned short;
using bf16x8 = __attribute__((ext_vector_type(8))) short;
using f32x4 = __attribute__((ext_vector_type(4))) float;

__device__ __forceinline__ unsigned short f2bf_rne(float x) {
  unsigned u = __builtin_bit_cast(unsigned, x);
  unsigned r = u + 0x7FFFu + ((u >> 16) & 1u);
  return (unsigned short)(r >> 16);
}
__device__ __forceinline__ float bf2f(unsigned short h) {
  unsigned u = ((unsigned)h) << 16;
  return __builtin_bit_cast(float, u);
}

// ================= CSR build: bucketed counting sort, coalesced IO =================
// Buckets of 256 nodes: NBK = ceil(N/256) = 391 for N=100000.
// pack = (dst & 255) << 17 | src   (src < 2^17)

#define NBK_MAX 400

// P1: bucket histogram (LDS-staged)
__global__ __launch_bounds__(256) void bucket_hist(const int* __restrict__ dst,
                                                   int* __restrict__ bcnt, int E, int nbk) {
  __shared__ int c[NBK_MAX];
  for (int j = threadIdx.x; j < nbk; j += 256) c[j] = 0;
  __syncthreads();
  for (int i = blockIdx.x * 256 + threadIdx.x; i < E; i += gridDim.x * 256)
    atomicAdd(&c[dst[i] >> 8], 1);
  __syncthreads();
  for (int j = threadIdx.x; j < nbk; j += 256)
    if (c[j]) atomicAdd(&bcnt[j], c[j]);
}

// P2: scan bucket counts -> boff, init gcur
__global__ void bucket_scan(const int* __restrict__ bcnt, int* __restrict__ boff,
                            int* __restrict__ gcur, int E, int nbk) {
  __shared__ int lds[512];
  int t = threadIdx.x;
  int v = (t < nbk) ? bcnt[t] : 0;
  lds[t] = v;
  __syncthreads();
  for (int s = 1; s < 512; s <<= 1) {
    int x = (t >= s) ? lds[t - s] : 0;
    __syncthreads();
    lds[t] += x;
    __syncthreads();
  }
  if (t < nbk) {
    boff[t] = lds[t] - v;
    gcur[t] = lds[t] - v;
  }
  if (t == 0) boff[nbk] = E;
}

// P3: partition edges into bucket-contiguous packed array
__global__ __launch_bounds__(256) void partition(const int* __restrict__ src,
                                                 const int* __restrict__ dst,
                                                 int* __restrict__ gcur,
                                                 unsigned* __restrict__ part, int E, int nbk) {
  __shared__ int cnt[NBK_MAX];
  __shared__ int base[NBK_MAX];
  const int t = threadIdx.x;
  for (int j = t; j < nbk; j += 256) cnt[j] = 0;
  __syncthreads();
  const int e0 = blockIdx.x * 4096;
  unsigned mypk[16];
  int mybk[16];
#pragma unroll
  for (int u = 0; u < 16; ++u) {
    int e = e0 + u * 256 + t;
    if (e < E) {
      int d = dst[e];
      mypk[u] = (unsigned)src[e] | ((unsigned)(d & 255) << 17);
      mybk[u] = d >> 8;
      atomicAdd(&cnt[mybk[u]], 1);
    } else {
      mybk[u] = -1;
    }
  }
  __syncthreads();
  for (int j = t; j < nbk; j += 256) {
    int c = cnt[j];
    base[j] = c ? atomicAdd(&gcur[j], c) : 0;
    cnt[j] = 0;
  }
  __syncthreads();
#pragma unroll
  for (int u = 0; u < 16; ++u) {
    if (mybk[u] >= 0) {
      int r = atomicAdd(&cnt[mybk[u]], 1);
      part[base[mybk[u]] + r] = mypk[u];
    }
  }
}

// P4: per-bucket LDS counting sort -> srcs (coalesced), offs, dinv
__global__ __launch_bounds__(256) void bucket_csr(const unsigned* __restrict__ part,
                                                  const int* __restrict__ boff,
                                                  int* __restrict__ offs, int* __restrict__ srcs,
                                                  float* __restrict__ dinv, int N, int E) {
  __shared__ unsigned pk[8192];
  __shared__ int ssrc[8192];
  __shared__ int cnt[256];
  __shared__ int offl[256];
  __shared__ int cur[256];
  const int b = blockIdx.x;
  const int t = threadIdx.x;
  const int e0 = boff[b];
  int ne = boff[b + 1] - e0;
  if (ne > 8192) ne = 8192;  // impossible for this input; guards LDS
  cnt[t] = 0;
  __syncthreads();
  for (int i = t; i < ne; i += 256) {
    unsigned v = part[e0 + i];
    pk[i] = v;
    atomicAdd(&cnt[v >> 17], 1);
  }
  __syncthreads();
  int vv = cnt[t];
  offl[t] = vv;
  __syncthreads();
  for (int s = 1; s < 256; s <<= 1) {
    int x = (t >= s) ? offl[t - s] : 0;
    __syncthreads();
    offl[t] += x;
    __syncthreads();
  }
  int excl = offl[t] - vv;
  cur[t] = excl;
  __syncthreads();
  for (int i = t; i < ne; i += 256) {
    unsigned p = pk[i];
    int dl = p >> 17;
    int r = atomicAdd(&cur[dl], 1);
    ssrc[r] = (int)(p & 0x1FFFF);
  }
  __syncthreads();
  for (int i = t; i < ne; i += 256) srcs[e0 + i] = ssrc[i];
  int node = b * 256 + t;
  if (node < N) {
    offs[node] = e0 + excl;
    dinv[node] = rsqrtf((float)(vv + 1));  // +1 self loop
  }
  if (b == gridDim.x - 1 && t == 0) offs[N] = E;
}

// ================= weight prep: transpose + hi/lo bf16 split =================

__global__ void wprep(const float* __restrict__ W, unsigned short* __restrict__ hi,
                      unsigned short* __restrict__ lo, int K, int N) {
  int i = blockIdx.x * 256 + threadIdx.x;
  if (i >= K * N) return;
  int k = i / N, n = i - k * N;
  float v = W[i];
  unsigned short h = f2bf_rne(v);
  hi[(size_t)n * K + k] = h;
  lo[(size_t)n * K + k] = f2bf_rne(v - bf2f(h));
}

// ================= MFMA GEMM =================
// Out[r,c] = bf16( dinv[r] * sum_k a(r,k)*W[k,c] ), a = optional BN+ReLU of A

template <int K, int BN, bool BNRELU>
__global__ __launch_bounds__(256) void mfma_gemm(const float* __restrict__ A,
                                                 const unsigned short* __restrict__ Bt_hi,
                                                 const unsigned short* __restrict__ Bt_lo,
                                                 const float* __restrict__ ss,
                                                 const float* __restrict__ dinv,
                                                 unsigned short* __restrict__ Out, int M) {
  constexpr int BM = 128;
  __shared__ unsigned short Ah[BM * 32];
  __shared__ unsigned short Al[BM * 32];
  __shared__ unsigned short Bh[BN * 32];
  __shared__ unsigned short Bl[BN * 32];

  const int tid = threadIdx.x;
  const int wave = tid >> 6;
  const int lane = tid & 63;
  const int lg = lane >> 4;
  const int lr = lane & 15;
  const int row0 = blockIdx.x * BM;

  f32x4 acc[2][BN / 16];
#pragma unroll
  for (int f = 0; f < 2; ++f)
#pragma unroll
    for (int j = 0; j < BN / 16; ++j) acc[f][j] = (f32x4){0.f, 0.f, 0.f, 0.f};

  for (int k0 = 0; k0 < K; k0 += 32) {
    __syncthreads();
#pragma unroll
    for (int it = 0; it < 4; ++it) {
      int m = it * 32 + (tid >> 3);
      int c2 = tid & 7;
      float4 v = {0.f, 0.f, 0.f, 0.f};
      if (row0 + m < M) v = *(const float4*)&A[(size_t)(row0 + m) * K + k0 + c2 * 4];
      if constexpr (BNRELU) {
        int kk = k0 + c2 * 4;
        float4 sc = *(const float4*)&ss[kk];
        float4 sh = *(const float4*)&ss[K + kk];
        v.x = fmaxf(0.f, fmaf(v.x, sc.x, sh.x));
        v.y = fmaxf(0.f, fmaf(v.y, sc.y, sh.y));
        v.z = fmaxf(0.f, fmaf(v.z, sc.z, sh.z));
        v.w = fmaxf(0.f, fmaf(v.w, sc.w, sh.w));
      }
      float vv[4] = {v.x, v.y, v.z, v.w};
      u16x4 h4, l4;
#pragma unroll
      for (int i = 0; i < 4; ++i) {
        unsigned short h = f2bf_rne(vv[i]);
        h4[i] = h;
        l4[i] = f2bf_rne(vv[i] - bf2f(h));
      }
      int pr = (m >> 1) & 3;
      int base = m * 32 + (((c2 >> 1) ^ pr) * 8) + (c2 & 1) * 4;
      *(u16x4*)&Ah[base] = h4;
      *(u16x4*)&Al[base] = l4;
    }
#pragma unroll
    for (int it = 0; it < BN / 64; ++it) {
      int n = it * 64 + (tid >> 2);
      int c = tid & 3;
      int pr = (n >> 1) & 3;
      int base = n * 32 + ((c ^ pr) * 8);
      *(u16x8*)&Bh[base] = *(const u16x8*)&Bt_hi[(size_t)n * K + k0 + c * 8];
      *(u16x8*)&Bl[base] = *(const u16x8*)&Bt_lo[(size_t)n * K + k0 + c * 8];
    }
    __syncthreads();

    bf16x8 afh[2], afl[2];
#pragma unroll
    for (int f = 0; f < 2; ++f) {
      int m = wave * 32 + f * 16 + lr;
      int pr = (m >> 1) & 3;
      int base = m * 32 + ((lg ^ pr) * 8);
      afh[f] = *(const bf16x8*)&Ah[base];
      afl[f] = *(const bf16x8*)&Al[base];
    }
#pragma unroll
    for (int j = 0; j < BN / 16; ++j) {
      int n = j * 16 + lr;
      int pr = (n >> 1) & 3;
      int base = n * 32 + ((lg ^ pr) * 8);
      bf16x8 bh = *(const bf16x8*)&Bh[base];
      bf16x8 bl = *(const bf16x8*)&Bl[base];
#pragma unroll
      for (int f = 0; f < 2; ++f) {
        acc[f][j] = __builtin_amdgcn_mfma_f32_16x16x32_bf16(afh[f], bh, acc[f][j], 0, 0, 0);
        acc[f][j] = __builtin_amdgcn_mfma_f32_16x16x32_bf16(afl[f], bh, acc[f][j], 0, 0, 0);
        acc[f][j] = __builtin_amdgcn_mfma_f32_16x16x32_bf16(afh[f], bl, acc[f][j], 0, 0, 0);
      }
    }
  }

#pragma unroll
  for (int f = 0; f < 2; ++f) {
#pragma unroll
    for (int r4 = 0; r4 < 4; ++r4) {
      int r = row0 + wave * 32 + f * 16 + lg * 4 + r4;
      if (r >= M) continue;
      float dv = dinv[r];
      size_t rb = (size_t)r * BN + lr;
#pragma unroll
      for (int j = 0; j < BN / 16; ++j) Out[rb + j * 16] = f2bf_rne(acc[f][j][r4] * dv);
    }
  }
}

// ================= aggregation (bf16 messages -> fp32), BN stats fused =================
// 64 nodes per block (16 iters x 4 waves)

template <bool STATS>
__global__ __launch_bounds__(256) void agg128(const unsigned short* __restrict__ g,
                                              const int* __restrict__ offs,
                                              const int* __restrict__ srcs,
                                              const float* __restrict__ dinv,
                                              float* __restrict__ out, float* __restrict__ stat,
                                              int N) {
  const int w = threadIdx.x >> 6;
  const int lane = threadIdx.x & 63;
  const size_t co = (size_t)lane * 2;
  float sx = 0.f, sy = 0.f, qx = 0.f, qy = 0.f;

  for (int it = 0; it < 16; ++it) {
    int node = blockIdx.x * 64 + it * 4 + w;
    if (node >= N) break;  // wave-uniform

    unsigned us = *(const unsigned*)&g[(size_t)node * 128 + co];
    float ax = __builtin_bit_cast(float, us << 16);
    float ay = __builtin_bit_cast(float, us & 0xffff0000u);

    int e0 = offs[node], e1 = offs[node + 1];
    int e = e0;
    for (; e + 4 <= e1; e += 4) {
      int s0 = srcs[e], s1 = srcs[e + 1], s2 = srcs[e + 2], s3 = srcs[e + 3];
      unsigned u0 = *(const unsigned*)&g[(size_t)s0 * 128 + co];
      unsigned u1 = *(const unsigned*)&g[(size_t)s1 * 128 + co];
      unsigned u2 = *(const unsigned*)&g[(size_t)s2 * 128 + co];
      unsigned u3 = *(const unsigned*)&g[(size_t)s3 * 128 + co];
      ax += __builtin_bit_cast(float, u0 << 16) + __builtin_bit_cast(float, u1 << 16) +
            __builtin_bit_cast(float, u2 << 16) + __builtin_bit_cast(float, u3 << 16);
      ay += __builtin_bit_cast(float, u0 & 0xffff0000u) +
            __builtin_bit_cast(float, u1 & 0xffff0000u) +
            __builtin_bit_cast(float, u2 & 0xffff0000u) +
            __builtin_bit_cast(float, u3 & 0xffff0000u);
    }
    for (; e < e1; ++e) {
      unsigned u = *(const unsigned*)&g[(size_t)srcs[e] * 128 + co];
      ax += __builtin_bit_cast(float, u << 16);
      ay += __builtin_bit_cast(float, u & 0xffff0000u);
    }
    float dv = dinv[node];
    float ox = ax * dv, oy = ay * dv;
    *(float2*)&out[(size_t)node * 128 + co] = (float2){ox, oy};
    if constexpr (STATS) {
      sx += ox;
      sy += oy;
      qx += ox * ox;
      qy += oy * oy;
    }
  }

  if constexpr (STATS) {
    __shared__ float red[4][64][4];
    red[w][lane][0] = sx;
    red[w][lane][1] = sy;
    red[w][lane][2] = qx;
    red[w][lane][3] = qy;
    __syncthreads();
    if (w == 0) {
      float a0 = red[0][lane][0] + red[1][lane][0] + red[2][lane][0] + red[3][lane][0];
      float a1 = red[0][lane][1] + red[1][lane][1] + red[2][lane][1] + red[3][lane][1];
      float a2 = red[0][lane][2] + red[1][lane][2] + red[2][lane][2] + red[3][lane][2];
      float a3 = red[0][lane][3] + red[1][lane][3] + red[2][lane][3] + red[3][lane][3];
      atomicAdd(&stat[co], a0);
      atomicAdd(&stat[co + 1], a1);
      atomicAdd(&stat[128 + co], a2);
      atomicAdd(&stat[128 + co + 1], a3);
    }
  }
}

// C=64: half-wave per edge, cross-half shuffle reduce
template <bool STATS>
__global__ __launch_bounds__(256) void agg64(const unsigned short* __restrict__ g,
                                             const int* __restrict__ offs,
                                             const int* __restrict__ srcs,
                                             const float* __restrict__ dinv,
                                             const float* __restrict__ bias,
                                             float* __restrict__ out, float* __restrict__ stat,
                                             int N) {
  const int w = threadIdx.x >> 6;
  const int lane = threadIdx.x & 63;
  const int half = lane >> 5;
  const int li = lane & 31;
  const size_t co = (size_t)li * 2;
  float sx = 0.f, sy = 0.f, qx = 0.f, qy = 0.f;

  for (int it = 0; it < 16; ++it) {
    int node = blockIdx.x * 64 + it * 4 + w;
    if (node >= N) break;  // wave-uniform

    float ax = 0.f, ay = 0.f;
    if (half == 0) {
      unsigned us = *(const unsigned*)&g[(size_t)node * 64 + co];
      ax = __builtin_bit_cast(float, us << 16);
      ay = __builtin_bit_cast(float, us & 0xffff0000u);
    }
    int e0 = offs[node], e1 = offs[node + 1];
    int e = e0 + half;
    for (; e + 6 < e1; e += 8) {
      int s0 = srcs[e], s1 = srcs[e + 2], s2 = srcs[e + 4], s3 = srcs[e + 6];
      unsigned u0 = *(const unsigned*)&g[(size_t)s0 * 64 + co];
      unsigned u1 = *(const unsigned*)&g[(size_t)s1 * 64 + co];
      unsigned u2 = *(const unsigned*)&g[(size_t)s2 * 64 + co];
      unsigned u3 = *(const unsigned*)&g[(size_t)s3 * 64 + co];
      ax += __builtin_bit_cast(float, u0 << 16) + __builtin_bit_cast(float, u1 << 16) +
            __builtin_bit_cast(float, u2 << 16) + __builtin_bit_cast(float, u3 << 16);
      ay += __builtin_bit_cast(float, u0 & 0xffff0000u) +
            __builtin_bit_cast(float, u1 & 0xffff0000u) +
            __builtin_bit_cast(float, u2 & 0xffff0000u) +
            __builtin_bit_cast(float, u3 & 0xffff0000u);
    }
    for (; e < e1; e += 2) {
      unsigned u = *(const unsigned*)&g[(size_t)srcs[e] * 64 + co];
      ax += __builtin_bit_cast(float, u << 16);
      ay += __builtin_bit_cast(float, u & 0xffff0000u);
    }
    ax += __shfl_xor(ax, 32);
    ay += __shfl_xor(ay, 32);
    if (half == 0) {
      float dv = dinv[node];
      float ox = ax * dv, oy = ay * dv;
      if (bias) {
        ox += bias[co];
        oy += bias[co + 1];
      }
      *(float2*)&out[(size_t)node * 64 + co] = (float2){ox, oy};
      if constexpr (STATS) {
        sx += ox;
        sy += oy;
        qx += ox * ox;
        qy += oy * oy;
      }
    }
  }

  if constexpr (STATS) {
    __shared__ float red[4][32][4];
    if (half == 0) {
      red[w][li][0] = sx;
      red[w][li][1] = sy;
      red[w][li][2] = qx;
      red[w][li][3] = qy;
    }
    __syncthreads();
    if (w == 0 && half == 0) {
      float a0 = red[0][li][0] + red[1][li][0] + red[2][li][0] + red[3][li][0];
      float a1 = red[0][li][1] + red[1][li][1] + red[2][li][1] + red[3][li][1];
      float a2 = red[0][li][2] + red[1][li][2] + red[2][li][2] + red[3][li][2];
      float a3 = red[0][li][3] + red[1][li][3] + red[2][li][3] + red[3][li][3];
      atomicAdd(&stat[co], a0);
      atomicAdd(&stat[co + 1], a1);
      atomicAdd(&stat[64 + co], a2);
      atomicAdd(&stat[64 + co + 1], a3);
    }
  }
}

// ================= BN finalize =================

template <int C>
__global__ void bn_finalize(const float* __restrict__ stat, const float* __restrict__ gamma,
                            const float* __restrict__ beta, float* __restrict__ ss, int N) {
  int c = threadIdx.x;
  if (c >= C) return;
  float mu = stat[c] / (float)N;
  float var = stat[C + c] / (float)N - mu * mu;
  float rs = rsqrtf(var + BN_EPS);
  float sc = gamma[c] * rs;
  ss[c] = sc;
  ss[C + c] = beta[c] - mu * sc;
}

// ================= launch =================

extern "C" void kernel_launch(void* const* d_in, const int* in_sizes, int n_in, void* d_out,
                              int out_size, void* d_ws, size_t ws_size, hipStream_t stream) {
  const float* x = (const float*)d_in[0];
  const int* ei = (const int*)d_in[1];
  const float* W1 = (const float*)d_in[2];
  // b1, b2 cancel in BN
  const float* gamma1 = (const float*)d_in[4];
  const float* beta1 = (const float*)d_in[5];
  const float* W2 = (const float*)d_in[6];
  const float* gamma2 = (const float*)d_in[8];
  const float* beta2 = (const float*)d_in[9];
  const float* W3 = (const float*)d_in[10];
  const float* b3 = (const float*)d_in[11];
  float* out = (float*)d_out;

  const int N = in_sizes[0] / IN_CH;  // 100000
  const int E = in_sizes[1] / 2;      // 1600000
  const int* e_src = ei;
  const int* e_dst = ei + E;
  const int nbk = (N + 255) >> 8;  // 391

  char* ws = (char*)d_ws;
  size_t off = 0;
  auto alloc = [&](size_t bytes) {
    size_t r = off;
    off += (bytes + 1023) & ~(size_t)1023;
    return r;
  };
  int* bcnt = (int*)(ws + alloc(NBK_MAX * 4));
  int* boff = (int*)(ws + alloc((NBK_MAX + 1) * 4));
  int* gcur = (int*)(ws + alloc(NBK_MAX * 4));
  unsigned* part = (unsigned*)(ws + alloc((size_t)E * 4));
  int* offs = (int*)(ws + alloc((size_t)(N + 1) * 4));
  int* srcs = (int*)(ws + alloc((size_t)E * 4));
  float* dinv = (float*)(ws + alloc((size_t)N * 4));
  unsigned short* Wt1h = (unsigned short*)(ws + alloc(256 * 128 * 2));
  unsigned short* Wt1l = (unsigned short*)(ws + alloc(256 * 128 * 2));
  unsigned short* Wt2h = (unsigned short*)(ws + alloc(128 * 64 * 2));
  unsigned short* Wt2l = (unsigned short*)(ws + alloc(128 * 64 * 2));
  unsigned short* Wt3h = (unsigned short*)(ws + alloc(64 * 64 * 2));
  unsigned short* Wt3l = (unsigned short*)(ws + alloc(64 * 64 * 2));
  float* stat1 = (float*)(ws + alloc(256 * 4));
  float* stat2 = (float*)(ws + alloc(128 * 4));
  float* ss1 = (float*)(ws + alloc(256 * 4));
  float* ss2 = (float*)(ws + alloc(128 * 4));
  unsigned short* g = (unsigned short*)(ws + alloc((size_t)N * 128 * 2));
  float* h = (float*)(ws + alloc((size_t)N * 128 * 4));

  hipMemsetAsync(bcnt, 0, NBK_MAX * 4, stream);
  hipMemsetAsync(stat1, 0, 256 * 4, stream);
  hipMemsetAsync(stat2, 0, 128 * 4, stream);

  // CSR build
  bucket_hist<<<2048, 256, 0, stream>>>(e_dst, bcnt, E, nbk);
  bucket_scan<<<1, 512, 0, stream>>>(bcnt, boff, gcur, E, nbk);
  partition<<<(E + 4095) / 4096, 256, 0, stream>>>(e_src, e_dst, gcur, part, E, nbk);
  bucket_csr<<<nbk, 256, 0, stream>>>(part, boff, offs, srcs, dinv, N, E);

  wprep<<<(256 * 128 + 255) / 256, 256, 0, stream>>>(W1, Wt1h, Wt1l, 256, 128);
  wprep<<<(128 * 64 + 255) / 256, 256, 0, stream>>>(W2, Wt2h, Wt2l, 128, 64);
  wprep<<<(64 * 64 + 255) / 256, 256, 0, stream>>>(W3, Wt3h, Wt3l, 64, 64);

  const int gM = (N + 127) / 128;    // 782
  const int gAgg = (N + 63) / 64;    // 1563

  // ---- layer 1: 256 -> 128 ----
  mfma_gemm<256, 128, false><<<gM, 256, 0, stream>>>(x, Wt1h, Wt1l, nullptr, dinv, g, N);
  agg128<true><<<gAgg, 256, 0, stream>>>(g, offs, srcs, dinv, h, stat1, N);
  bn_finalize<128><<<1, 128, 0, stream>>>(stat1, gamma1, beta1, ss1, N);

  // ---- layer 2: 128 -> 64 (BN+ReLU fused into A staging) ----
  mfma_gemm<128, 64, true><<<gM, 256, 0, stream>>>(h, Wt2h, Wt2l, ss1, dinv, g, N);
  agg64<true><<<gAgg, 256, 0, stream>>>(g, offs, srcs, dinv, nullptr, h, stat2, N);
  bn_finalize<64><<<1, 64, 0, stream>>>(stat2, gamma2, beta2, ss2, N);

  // ---- layer 3: 64 -> 64 ----
  mfma_gemm<64, 64, true><<<gM, 256, 0, stream>>>(h, Wt3h, Wt3l, ss2, dinv, g, N);
  agg64<false><<<gAgg, 256, 0, stream>>>(g, offs, srcs, dinv, b3, out, nullptr, N);
}